// Round 1
// baseline (1196.709 us; speedup 1.0000x reference)
//
#include <hip/hip_runtime.h>
#include <hip/hip_bf16.h>

// Problem constants (B,S,D,H fixed by the reference).
constexpr int CB = 2;        // batch
constexpr int CS = 2048;     // seq
constexpr int CD = 1024;     // hidden
constexpr int CH = 16;       // heads
constexpr int CHD = 64;      // head dim
constexpr float CSCALE = 0.125f;  // 64^-0.5

// ---------------------------------------------------------------------------
// Generic 128x64-tile f32 GEMM:  C[m][n] = sum_k A[m][k] * W[k][n]
// A is row-major [M][K] with ld == K (K = 1024 for both uses).
// If Cdirect != nullptr: write C row-major [M][1024] at (m, n0+...).
// Else: scatter the 64-wide n-block (exactly one head of q/k/v) into
// Q/K/V workspace laid out [B][H][S][HD].
// 256 threads: tx = tid&15 (4 cols each), ty = tid>>4 (8 rows each).
// ---------------------------------------------------------------------------
__global__ __launch_bounds__(256) void gemm128x64(
    const float* __restrict__ A, const float* __restrict__ W,
    int K, int ldw,
    float* __restrict__ Cq, float* __restrict__ Ck, float* __restrict__ Cv,
    float* __restrict__ Cdirect)
{
    __shared__ float At[16][132];   // A-tile transposed: At[k][m], +4 pad
    __shared__ float Wt[16][64];    // W-tile: Wt[k][n]

    const int tid = threadIdx.x;
    const int tx = tid & 15, ty = tid >> 4;
    const int m0 = blockIdx.y * 128;
    const int n0 = blockIdx.x * 64;

    float acc[8][4] = {};

    for (int k0 = 0; k0 < K; k0 += 16) {
        // Stage A tile (128 rows x 16 k) transposed into LDS.
#pragma unroll
        for (int r = 0; r < 2; ++r) {
            int f = tid + r * 256;            // float4 index 0..511
            int row = f >> 2;                 // 0..127
            int c4 = (f & 3) << 2;            // 0,4,8,12
            const float4 v = *(const float4*)(A + (size_t)(m0 + row) * K + k0 + c4);
            At[c4 + 0][row] = v.x; At[c4 + 1][row] = v.y;
            At[c4 + 2][row] = v.z; At[c4 + 3][row] = v.w;
        }
        // Stage W tile (16 k x 64 n).
        {
            int row = tid >> 4;               // 0..15
            int c4 = (tid & 15) << 2;         // 0..60
            *(float4*)&Wt[row][c4] =
                *(const float4*)(W + (size_t)(k0 + row) * ldw + n0 + c4);
        }
        __syncthreads();

#pragma unroll
        for (int kk = 0; kk < 16; ++kk) {
            const float4 a0 = *(const float4*)&At[kk][ty * 8];
            const float4 a1 = *(const float4*)&At[kk][ty * 8 + 4];
            const float4 b0 = *(const float4*)&Wt[kk][tx * 4];
            const float a[8] = {a0.x, a0.y, a0.z, a0.w, a1.x, a1.y, a1.z, a1.w};
            const float b[4] = {b0.x, b0.y, b0.z, b0.w};
#pragma unroll
            for (int i = 0; i < 8; ++i)
#pragma unroll
                for (int j = 0; j < 4; ++j)
                    acc[i][j] += a[i] * b[j];
        }
        __syncthreads();
    }

    if (Cdirect) {
#pragma unroll
        for (int i = 0; i < 8; ++i) {
            float4 v = make_float4(acc[i][0], acc[i][1], acc[i][2], acc[i][3]);
            *(float4*)(Cdirect + (size_t)(m0 + ty * 8 + i) * 1024 + n0 + tx * 4) = v;
        }
    } else {
        // n0 is a multiple of 64 -> whole block is one head of one of q/k/v.
        const int which = n0 >> 10;           // 0=q 1=k 2=v
        const int h = (n0 & 1023) >> 6;       // head
        float* dst = (which == 0) ? Cq : ((which == 1) ? Ck : Cv);
        const int b = m0 >> 11;               // 128 | 2048, so one b per block
        const int s0 = (m0 & 2047) + ty * 8;
#pragma unroll
        for (int i = 0; i < 8; ++i) {
            float4 v = make_float4(acc[i][0], acc[i][1], acc[i][2], acc[i][3]);
            *(float4*)(dst + (((size_t)b * CH + h) * CS + (s0 + i)) * CHD + tx * 4) = v;
        }
    }
}

// ---------------------------------------------------------------------------
// Flash-style causal attention, f32. One block per (q-tile of 64, b*h).
// Q,K,V in [B][H][S][HD]; output written directly in [B][S][D] layout so the
// out-projection can consume it as a plain row-major matrix.
// 256 threads: tx = tid&15 (4 k-cols / 4 d-cols each), ty = tid>>4 (4 q-rows).
// ---------------------------------------------------------------------------
__global__ __launch_bounds__(256) void attn_kernel(
    const float* __restrict__ Q, const float* __restrict__ K,
    const float* __restrict__ V, float* __restrict__ O)
{
    __shared__ float Qs[64][68];   // [q][d]
    __shared__ float Kt[64][68];   // transposed: [d][k]  (2-way-free B reads)
    __shared__ float Vs[64][68];   // [k][d]
    __shared__ float Ps[64][68];   // [q][k]

    const int tid = threadIdx.x;
    const int tx = tid & 15, ty = tid >> 4;
    const int qt = gridDim.x - 1 - blockIdx.x;   // long blocks dispatch first
    const int bh = blockIdx.y;

    const float* Qp = Q + (size_t)bh * CS * CHD;
    const float* Kp = K + (size_t)bh * CS * CHD;
    const float* Vp = V + (size_t)bh * CS * CHD;

    // Load Q tile (64 x 64).
#pragma unroll
    for (int r = 0; r < 4; ++r) {
        int f = tid + r * 256;        // float4 idx 0..1023
        int row = f >> 4;             // 0..63
        int c4 = (f & 15) << 2;       // 0..60
        *(float4*)&Qs[row][c4] = *(const float4*)(Qp + (size_t)(qt * 64 + row) * CHD + c4);
    }

    float o[4][4] = {};
    float mi[4], li[4];
#pragma unroll
    for (int i = 0; i < 4; ++i) { mi[i] = -1e30f; li[i] = 0.f; }

    const int nkt = qt + 1;
    for (int kt = 0; kt < nkt; ++kt) {
        __syncthreads();   // prior-iteration Ps/Vs reads done; Qs store visible
        // Load K (transposed into Kt) and V tiles.
#pragma unroll
        for (int r = 0; r < 4; ++r) {
            int f = tid + r * 256;
            int row = f >> 4;
            int c4 = (f & 15) << 2;
            const float4 kv = *(const float4*)(Kp + (size_t)(kt * 64 + row) * CHD + c4);
            Kt[c4 + 0][row] = kv.x; Kt[c4 + 1][row] = kv.y;
            Kt[c4 + 2][row] = kv.z; Kt[c4 + 3][row] = kv.w;
            *(float4*)&Vs[row][c4] = *(const float4*)(Vp + (size_t)(kt * 64 + row) * CHD + c4);
        }
        __syncthreads();

        // S = Q K^T (rows ty*4+i, cols tx*4+j), 4x4x4 micro-matmul over d.
        float s[4][4] = {};
        for (int d4 = 0; d4 < 64; d4 += 4) {
            float q_[4][4], k_[4][4];
#pragma unroll
            for (int i = 0; i < 4; ++i) {
                const float4 qv = *(const float4*)&Qs[ty * 4 + i][d4];
                q_[i][0] = qv.x; q_[i][1] = qv.y; q_[i][2] = qv.z; q_[i][3] = qv.w;
            }
#pragma unroll
            for (int c = 0; c < 4; ++c) {
                const float4 kv = *(const float4*)&Kt[d4 + c][tx * 4];
                k_[c][0] = kv.x; k_[c][1] = kv.y; k_[c][2] = kv.z; k_[c][3] = kv.w;
            }
#pragma unroll
            for (int i = 0; i < 4; ++i)
#pragma unroll
                for (int c = 0; c < 4; ++c)
#pragma unroll
                    for (int j = 0; j < 4; ++j)
                        s[i][j] += q_[i][c] * k_[c][j];
        }

        // Scale + causal mask (only the diagonal tile needs masking).
        const bool diag = (kt == qt);
#pragma unroll
        for (int i = 0; i < 4; ++i)
#pragma unroll
            for (int j = 0; j < 4; ++j) {
                s[i][j] *= CSCALE;
                if (diag && (tx * 4 + j) > (ty * 4 + i)) s[i][j] = -1e30f;
            }

        // Online softmax update (rows owned by 16 tx-lanes within one wave).
#pragma unroll
        for (int i = 0; i < 4; ++i) {
            float rm = fmaxf(fmaxf(s[i][0], s[i][1]), fmaxf(s[i][2], s[i][3]));
#pragma unroll
            for (int off = 1; off < 16; off <<= 1) rm = fmaxf(rm, __shfl_xor(rm, off));
            const float mnew = fmaxf(mi[i], rm);
            const float alpha = __expf(mi[i] - mnew);
            float rs = 0.f;
#pragma unroll
            for (int j = 0; j < 4; ++j) { s[i][j] = __expf(s[i][j] - mnew); rs += s[i][j]; }
#pragma unroll
            for (int off = 1; off < 16; off <<= 1) rs += __shfl_xor(rs, off);
            li[i] = li[i] * alpha + rs;
            mi[i] = mnew;
#pragma unroll
            for (int j = 0; j < 4; ++j) o[i][j] *= alpha;
        }

        // Stage P, then PV.
#pragma unroll
        for (int i = 0; i < 4; ++i)
            *(float4*)&Ps[ty * 4 + i][tx * 4] = make_float4(s[i][0], s[i][1], s[i][2], s[i][3]);
        __syncthreads();

        for (int kk = 0; kk < 64; kk += 4) {
            float p_[4][4], v_[4][4];
#pragma unroll
            for (int i = 0; i < 4; ++i) {
                const float4 pv = *(const float4*)&Ps[ty * 4 + i][kk];
                p_[i][0] = pv.x; p_[i][1] = pv.y; p_[i][2] = pv.z; p_[i][3] = pv.w;
            }
#pragma unroll
            for (int c = 0; c < 4; ++c) {
                const float4 vv = *(const float4*)&Vs[kk + c][tx * 4];
                v_[c][0] = vv.x; v_[c][1] = vv.y; v_[c][2] = vv.z; v_[c][3] = vv.w;
            }
#pragma unroll
            for (int i = 0; i < 4; ++i)
#pragma unroll
                for (int c = 0; c < 4; ++c)
#pragma unroll
                    for (int j = 0; j < 4; ++j)
                        o[i][j] += p_[i][c] * v_[c][j];
        }
    }

    // Normalize and write to [B][S][D] (d = h*64 + tx*4+j).
    const int b = bh >> 4, h = bh & 15;
#pragma unroll
    for (int i = 0; i < 4; ++i) {
        const float inv = 1.f / li[i];
        const int srow = qt * 64 + ty * 4 + i;
        float4 v = make_float4(o[i][0] * inv, o[i][1] * inv, o[i][2] * inv, o[i][3] * inv);
        *(float4*)(O + ((size_t)b * CS + srow) * CD + h * CHD + tx * 4) = v;
    }
}

// ---------------------------------------------------------------------------
extern "C" void kernel_launch(void* const* d_in, const int* in_sizes, int n_in,
                              void* d_out, int out_size, void* d_ws, size_t ws_size,
                              hipStream_t stream)
{
    const float* x     = (const float*)d_in[0];   // (B,S,D)
    const float* w_qkv = (const float*)d_in[1];   // (D,3D)
    const float* w_out = (const float*)d_in[2];   // (D,D)
    float* out = (float*)d_out;                   // (B,S,D)

    const size_t per = (size_t)CB * CH * CS * CHD;   // 4.19M floats
    float* Qws = (float*)d_ws;
    float* Kws = Qws + per;
    float* Vws = Kws + per;
    float* Ows = Vws + per;   // attention output, [B][S][D]

    dim3 blk(256);
    // 1) QKV projection: M=4096, N=3072, K=1024, scatter into Q/K/V heads.
    gemm128x64<<<dim3(3072 / 64, 4096 / 128), blk, 0, stream>>>(
        x, w_qkv, 1024, 3072, Qws, Kws, Vws, nullptr);
    // 2) Flash causal attention.
    attn_kernel<<<dim3(CS / 64, CB * CH), blk, 0, stream>>>(Qws, Kws, Vws, Ows);
    // 3) Output projection: M=4096, N=1024, K=1024, direct write.
    gemm128x64<<<dim3(1024 / 64, 4096 / 128), blk, 0, stream>>>(
        Ows, w_out, 1024, 1024, nullptr, nullptr, nullptr, out);
}

// Round 2
// 265.417 us; speedup vs baseline: 4.5088x; 4.5088x over previous
//
#include <hip/hip_runtime.h>
#include <hip/hip_bf16.h>
#include <stdint.h>

typedef unsigned short u16;
typedef __attribute__((ext_vector_type(8))) short short8;   // 8 bf16 = 4 VGPR (MFMA A/B frag)
typedef __attribute__((ext_vector_type(4))) short short4e;  // 8B packed store
typedef __attribute__((ext_vector_type(4))) float f32x4;    // MFMA C/D frag

constexpr int CB = 2, CS = 2048, CD = 1024, CH = 16, CHD = 64;
constexpr float CSCALE = 0.125f;

__device__ __forceinline__ u16 f2bf(float f) {
    unsigned u = __float_as_uint(f);
    u += 0x7fffu + ((u >> 16) & 1u);     // RNE
    return (u16)(u >> 16);
}

// ---------------------------------------------------------------------------
// f32 -> bf16 elementwise (x). 8 elems/thread, exact grid.
// ---------------------------------------------------------------------------
__global__ __launch_bounds__(256) void cvt_x(const float* __restrict__ X, u16* __restrict__ Y) {
    const int i = (blockIdx.x * 256 + threadIdx.x) * 8;
    const float4 v0 = *(const float4*)(X + i);
    const float4 v1 = *(const float4*)(X + i + 4);
    short8 r;
    r[0] = (short)f2bf(v0.x); r[1] = (short)f2bf(v0.y);
    r[2] = (short)f2bf(v0.z); r[3] = (short)f2bf(v0.w);
    r[4] = (short)f2bf(v1.x); r[5] = (short)f2bf(v1.y);
    r[6] = (short)f2bf(v1.z); r[7] = (short)f2bf(v1.w);
    *(short8*)(Y + i) = r;
}

// ---------------------------------------------------------------------------
// Transpose + convert: W [1024][N] f32  ->  Bt [N][1024] bf16.  64x64 tiles.
// ---------------------------------------------------------------------------
__global__ __launch_bounds__(256) void txw(const float* __restrict__ W, u16* __restrict__ Bt,
                                           int ldw) {
    __shared__ u16 T[64][80];   // [n][k], 160B rows (16B aligned)
    const int t = threadIdx.x;
    const int n0 = blockIdx.x * 64, k0 = blockIdx.y * 64;
    const int r = t >> 4, c4 = (t & 15) * 4;
#pragma unroll
    for (int p = 0; p < 4; ++p) {
        const int kr = r + p * 16;
        const float4 v = *(const float4*)(W + (size_t)(k0 + kr) * ldw + n0 + c4);
        T[c4 + 0][kr] = f2bf(v.x); T[c4 + 1][kr] = f2bf(v.y);
        T[c4 + 2][kr] = f2bf(v.z); T[c4 + 3][kr] = f2bf(v.w);
    }
    __syncthreads();
    const int rr = t >> 2, cc = (t & 3) * 16;
    const short8 a = *(const short8*)((const char*)&T[0][0] + rr * 160 + cc * 2);
    const short8 b = *(const short8*)((const char*)&T[0][0] + rr * 160 + cc * 2 + 16);
    u16* dst = Bt + (size_t)(n0 + rr) * 1024 + k0 + cc;
    *(short8*)dst = a;
    *(short8*)(dst + 8) = b;
}

// ---------------------------------------------------------------------------
// bf16 MFMA GEMM, 128x128 tile, BK=32, 4 waves (2x2), double-buffered LDS,
// reg-staged global->LDS, 1 barrier per K-step.  K fixed = 1024.
// A [M][1024] bf16 row-major, Bt [N][1024] bf16 row-major (i.e. B transposed).
// mode 0: scatter QKV (N-block of 128 = 2 heads; per-wave 64 cols = 1 head).
// mode 1: f32 direct write to Cf [M][1024].
// ---------------------------------------------------------------------------
__global__ __launch_bounds__(256) void gemm_mfma(
    const u16* __restrict__ A, const u16* __restrict__ Bt, int mode,
    u16* __restrict__ Qws, u16* __restrict__ Kws, u16* __restrict__ Vtws,
    float* __restrict__ Cf)
{
    __shared__ u16 SB[2][8192];   // per buffer: A-tile [128][32] | B-tile [128][32]
    const int tid = threadIdx.x;
    const int w = tid >> 6, lane = tid & 63;
    const int l15 = lane & 15, l4 = lane >> 4;
    const int wr = w >> 1, wc = w & 1;
    const int n0 = blockIdx.x * 128, m0 = blockIdx.y * 128;

    f32x4 acc[4][4];
    const f32x4 zf = {0.f, 0.f, 0.f, 0.f};
#pragma unroll
    for (int i = 0; i < 4; ++i)
#pragma unroll
        for (int j = 0; j < 4; ++j) acc[i][j] = zf;

    short8 stg[4];
    // chunk c = tid + it*256 (c<512: A, else B); 16B per chunk, linear LDS.
#define GEMM_ISSUE(K0)                                                          \
    {                                                                           \
        _Pragma("unroll")                                                       \
        for (int it = 0; it < 4; ++it) {                                        \
            const int c = tid + it * 256;                                       \
            const u16* src;                                                     \
            if (c < 512) { const int row = c >> 2, cs = c & 3;                  \
                src = A + (size_t)(m0 + row) * 1024 + (K0) + cs * 8; }          \
            else { const int c2 = c - 512; const int row = c2 >> 2, cs = c2 & 3;\
                src = Bt + (size_t)(n0 + row) * 1024 + (K0) + cs * 8; }         \
            stg[it] = *(const short8*)src;                                      \
        }                                                                       \
    }
#define GEMM_WRITE(BUF)                                                         \
    {                                                                           \
        _Pragma("unroll")                                                       \
        for (int it = 0; it < 4; ++it) {                                        \
            const int c = tid + it * 256;                                       \
            *(short8*)&SB[BUF][c * 8] = stg[it];                                \
        }                                                                       \
    }

    GEMM_ISSUE(0);
    GEMM_WRITE(0);
    __syncthreads();

    for (int t = 0; t < 32; ++t) {
        const int cur = t & 1;
        if (t < 31) GEMM_ISSUE((t + 1) * 32);

        const u16* Al = &SB[cur][0];
        const u16* Bl = &SB[cur][4096];
        short8 a[4], b[4];
#pragma unroll
        for (int i = 0; i < 4; ++i)
            a[i] = *(const short8*)(Al + (wr * 64 + i * 16 + l15) * 32 + l4 * 8);
#pragma unroll
        for (int j = 0; j < 4; ++j)
            b[j] = *(const short8*)(Bl + (wc * 64 + j * 16 + l15) * 32 + l4 * 8);
#pragma unroll
        for (int i = 0; i < 4; ++i)
#pragma unroll
            for (int j = 0; j < 4; ++j)
                acc[i][j] = __builtin_amdgcn_mfma_f32_16x16x32_bf16(a[i], b[j], acc[i][j], 0, 0, 0);

        if (t < 31) GEMM_WRITE(cur ^ 1);
        __syncthreads();
    }

    // Epilogue.  C/D layout: col = lane&15, row = (lane>>4)*4 + reg  [verified m89/m91].
    if (mode == 1) {
#pragma unroll
        for (int i = 0; i < 4; ++i)
#pragma unroll
            for (int j = 0; j < 4; ++j)
#pragma unroll
                for (int r = 0; r < 4; ++r)
                    Cf[(size_t)(m0 + wr * 64 + i * 16 + l4 * 4 + r) * 1024 +
                       n0 + wc * 64 + j * 16 + l15] = acc[i][j][r];
    } else {
        const int e0 = n0 + wc * 64;          // 0..3071, multiple of 64 -> one head
        const int which = e0 >> 10;           // 0=q 1=k 2=v
        const int h = (e0 >> 6) & 15;
        const int b = m0 >> 11;
        const int sbase = (m0 & 2047) + wr * 64;
        if (which == 2) {
            // V stored TRANSPOSED: Vt[(b*16+h)][hd][s], ld = 2048.
#pragma unroll
            for (int i = 0; i < 4; ++i)
#pragma unroll
                for (int j = 0; j < 4; ++j) {
                    const int hd = j * 16 + l15;
                    const int s4 = sbase + i * 16 + l4 * 4;
                    short4e p;
                    p[0] = (short)f2bf(acc[i][j][0]); p[1] = (short)f2bf(acc[i][j][1]);
                    p[2] = (short)f2bf(acc[i][j][2]); p[3] = (short)f2bf(acc[i][j][3]);
                    *(short4e*)(Vtws + ((size_t)(b * 16 + h) * 64 + hd) * 2048 + s4) = p;
                }
        } else {
            u16* dst = which ? Kws : Qws;
#pragma unroll
            for (int i = 0; i < 4; ++i)
#pragma unroll
                for (int j = 0; j < 4; ++j)
#pragma unroll
                    for (int r = 0; r < 4; ++r) {
                        const int s = sbase + i * 16 + l4 * 4 + r;
                        dst[((size_t)(b * 16 + h) * 2048 + s) * 64 + j * 16 + l15] =
                            f2bf(acc[i][j][r]);
                    }
        }
    }
#undef GEMM_ISSUE
#undef GEMM_WRITE
}

// ---------------------------------------------------------------------------
// MFMA flash attention. 4 waves x 32 q-rows (QBLK=128), KVBLK=64, causal.
// Q,K bf16 [BH][S][64]; Vt bf16 [BH][64][S]; O bf16 [B][S][D].
// K/V LDS tiles XOR-swizzled (byte ^= (row&7)<<4) -> conflict-free ds_read_b128.
// ---------------------------------------------------------------------------
__global__ __launch_bounds__(256) void attn_mfma(
    const u16* __restrict__ Qg, const u16* __restrict__ Kg,
    const u16* __restrict__ Vtg, u16* __restrict__ Og)
{
    __shared__ u16 KV[2][8192];    // per buffer: K[64][64] | V^T[64][64], swizzled
    __shared__ u16 Pl[4][2048];    // per-wave P [32][64], swizzled

    const int tid = threadIdx.x;
    const int w = tid >> 6, lane = tid & 63;
    const int l15 = lane & 15, l4 = lane >> 4;
    const int qt = (int)gridDim.x - 1 - (int)blockIdx.x;   // heavy tiles first
    const int bh = blockIdx.y;
    const u16* Qp = Qg + (size_t)bh * CS * CHD;
    const u16* Kp = Kg + (size_t)bh * CS * CHD;
    const u16* Vp = Vtg + (size_t)bh * CHD * CS;
    const int q0 = qt * 128 + w * 32;

    // Q fragments hoisted to registers (A-frag: row=lane&15, k=(lane>>4)*8+j).
    short8 aq[2][2];
#pragma unroll
    for (int i = 0; i < 2; ++i)
#pragma unroll
        for (int h = 0; h < 2; ++h)
            aq[i][h] = *(const short8*)(Qp + (size_t)(q0 + i * 16 + l15) * 64 + h * 32 + l4 * 8);

    const f32x4 zf = {0.f, 0.f, 0.f, 0.f};
    f32x4 o[2][4];
    float mi[2][4], li[2][4];
#pragma unroll
    for (int i = 0; i < 2; ++i) {
#pragma unroll
        for (int j = 0; j < 4; ++j) o[i][j] = zf;
#pragma unroll
        for (int r = 0; r < 4; ++r) { mi[i][r] = -1e30f; li[i][r] = 0.f; }
    }

    const int nkt = 2 * qt + 2;
    short8 stg[4];

    // chunk c = tid + it*256; it 0,1 -> K tile, it 2,3 -> V tile.
#define ATTN_ISSUE(K0)                                                           \
    {                                                                            \
        _Pragma("unroll")                                                        \
        for (int it = 0; it < 4; ++it) {                                         \
            const int c = tid + it * 256;                                        \
            const int ob = c * 16;                                               \
            const u16* src;                                                      \
            if (ob < 8192) { const int row = ob >> 7, cs = (ob >> 4) & 7;        \
                src = Kp + (size_t)((K0) + row) * 64 + cs * 8; }                 \
            else { const int o2 = ob - 8192; const int row = o2 >> 7,            \
                cs = (o2 >> 4) & 7;                                              \
                src = Vp + (size_t)row * CS + (K0) + cs * 8; }                   \
            stg[it] = *(const short8*)src;                                       \
        }                                                                        \
    }
#define ATTN_WRITE(BUF)                                                          \
    {                                                                            \
        _Pragma("unroll")                                                        \
        for (int it = 0; it < 4; ++it) {                                         \
            const int c = tid + it * 256;                                        \
            const int ob = c * 16;                                               \
            int db;                                                              \
            if (ob < 8192) { const int row = ob >> 7; db = ob ^ ((row & 7) << 4); } \
            else { const int o2 = ob - 8192; const int row = o2 >> 7;            \
                db = 8192 + (o2 ^ ((row & 7) << 4)); }                           \
            *(short8*)((char*)&KV[BUF][0] + db) = stg[it];                       \
        }                                                                        \
    }

    ATTN_ISSUE(0);
    ATTN_WRITE(0);
    __syncthreads();

    for (int kt = 0; kt < nkt; ++kt) {
        const int k0 = kt * 64;
        const int cur = kt & 1;
        if (kt + 1 < nkt) ATTN_ISSUE((kt + 1) * 64);

        if (k0 <= q0 + 31) {   // this wave has unmasked work in the tile
            const char* Kl = (const char*)&KV[cur][0];
            const char* Vl = (const char*)&KV[cur][4096];

            // S = Q K^T  (f32 accum)
            f32x4 s[2][4];
#pragma unroll
            for (int i = 0; i < 2; ++i)
#pragma unroll
                for (int j = 0; j < 4; ++j) s[i][j] = zf;
#pragma unroll
            for (int j = 0; j < 4; ++j) {
                const int krow = j * 16 + l15;
                const short8 bk0 = *(const short8*)(Kl + (krow * 128 + ((l4) ^ (krow & 7)) * 16));
                const short8 bk1 = *(const short8*)(Kl + (krow * 128 + ((4 + l4) ^ (krow & 7)) * 16));
#pragma unroll
                for (int i = 0; i < 2; ++i) {
                    s[i][j] = __builtin_amdgcn_mfma_f32_16x16x32_bf16(aq[i][0], bk0, s[i][j], 0, 0, 0);
                    s[i][j] = __builtin_amdgcn_mfma_f32_16x16x32_bf16(aq[i][1], bk1, s[i][j], 0, 0, 0);
                }
            }

            // scale + causal mask + online softmax
            const bool edge = (k0 + 63 > q0);
#pragma unroll
            for (int i = 0; i < 2; ++i) {
#pragma unroll
                for (int r = 0; r < 4; ++r) {
                    const int qrow = q0 + i * 16 + l4 * 4 + r;
                    float v[4];
#pragma unroll
                    for (int j = 0; j < 4; ++j) {
                        v[j] = s[i][j][r] * CSCALE;
                        if (edge && (k0 + j * 16 + l15) > qrow) v[j] = -1e30f;
                    }
                    float rm = fmaxf(fmaxf(v[0], v[1]), fmaxf(v[2], v[3]));
                    rm = fmaxf(rm, __shfl_xor(rm, 1));
                    rm = fmaxf(rm, __shfl_xor(rm, 2));
                    rm = fmaxf(rm, __shfl_xor(rm, 4));
                    rm = fmaxf(rm, __shfl_xor(rm, 8));
                    const float mn = fmaxf(mi[i][r], rm);
                    const float al = __expf(mi[i][r] - mn);
                    mi[i][r] = mn;
                    float rs = 0.f;
#pragma unroll
                    for (int j = 0; j < 4; ++j) { v[j] = __expf(v[j] - mn); rs += v[j]; }
                    rs += __shfl_xor(rs, 1);
                    rs += __shfl_xor(rs, 2);
                    rs += __shfl_xor(rs, 4);
                    rs += __shfl_xor(rs, 8);
                    li[i][r] = li[i][r] * al + rs;
#pragma unroll
                    for (int j = 0; j < 4; ++j) { o[i][j][r] *= al; s[i][j][r] = v[j]; }
                }
            }

            // P -> per-wave LDS (bf16, swizzled), then A-frags for PV.
            char* Pw = (char*)&Pl[w][0];
#pragma unroll
            for (int i = 0; i < 2; ++i)
#pragma unroll
                for (int j = 0; j < 4; ++j)
#pragma unroll
                    for (int r = 0; r < 4; ++r) {
                        const int prow = i * 16 + l4 * 4 + r;
                        const int pb = (prow * 128 + (j * 16 + l15) * 2) ^ ((prow & 7) << 4);
                        *(u16*)(Pw + pb) = f2bf(s[i][j][r]);
                    }
            short8 ap[2][2];
#pragma unroll
            for (int i = 0; i < 2; ++i)
#pragma unroll
                for (int kh = 0; kh < 2; ++kh) {
                    const int prow = i * 16 + l15;
                    const int pb = (prow * 128 + kh * 64 + l4 * 16) ^ ((prow & 7) << 4);
                    ap[i][kh] = *(const short8*)(Pw + pb);
                }
            // O += P V   (V^T rows give B-frag: lane holds V[k][dcol])
#pragma unroll
            for (int j = 0; j < 4; ++j) {
                const int vrow = j * 16 + l15;
                const short8 bv0 = *(const short8*)(Vl + (vrow * 128 + ((l4) ^ (vrow & 7)) * 16));
                const short8 bv1 = *(const short8*)(Vl + (vrow * 128 + ((4 + l4) ^ (vrow & 7)) * 16));
#pragma unroll
                for (int i = 0; i < 2; ++i) {
                    o[i][j] = __builtin_amdgcn_mfma_f32_16x16x32_bf16(ap[i][0], bv0, o[i][j], 0, 0, 0);
                    o[i][j] = __builtin_amdgcn_mfma_f32_16x16x32_bf16(ap[i][1], bv1, o[i][j], 0, 0, 0);
                }
            }
        }

        if (kt + 1 < nkt) ATTN_WRITE(cur ^ 1);
        __syncthreads();
    }

    // Normalize + write O bf16 in [B][S][D].
    const int b = bh >> 4, h = bh & 15;
#pragma unroll
    for (int i = 0; i < 2; ++i)
#pragma unroll
        for (int r = 0; r < 4; ++r) {
            const float inv = 1.f / li[i][r];
            const int srow = q0 + i * 16 + l4 * 4 + r;
#pragma unroll
            for (int j = 0; j < 4; ++j)
                Og[((size_t)(b * CS + srow)) * CD + h * 64 + j * 16 + l15] =
                    f2bf(o[i][j][r] * inv);
        }
#undef ATTN_ISSUE
#undef ATTN_WRITE
}

// ---------------------------------------------------------------------------
extern "C" void kernel_launch(void* const* d_in, const int* in_sizes, int n_in,
                              void* d_out, int out_size, void* d_ws, size_t ws_size,
                              hipStream_t stream)
{
    const float* x     = (const float*)d_in[0];   // (B,S,D)
    const float* w_qkv = (const float*)d_in[1];   // (D,3D)
    const float* w_out = (const float*)d_in[2];   // (D,D)
    float* out = (float*)d_out;                   // (B,S,D) f32

    u16* xb    = (u16*)d_ws;                      // [4096][1024]
    u16* wqkvT = xb    + (size_t)4096 * 1024;     // [3072][1024]
    u16* woutT = wqkvT + (size_t)3072 * 1024;     // [1024][1024]
    u16* Qws   = woutT + (size_t)1024 * 1024;     // [32][2048][64]
    u16* Kws   = Qws   + (size_t)32 * 2048 * 64;
    u16* Vtws  = Kws   + (size_t)32 * 2048 * 64;  // [32][64][2048]
    u16* Ob    = Vtws  + (size_t)32 * 2048 * 64;  // [4096][1024]

    cvt_x<<<2048, 256, 0, stream>>>(x, xb);
    txw<<<dim3(48, 16), 256, 0, stream>>>(w_qkv, wqkvT, 3072);
    txw<<<dim3(16, 16), 256, 0, stream>>>(w_out, woutT, 1024);

    gemm_mfma<<<dim3(24, 32), 256, 0, stream>>>(xb, wqkvT, 0, Qws, Kws, Vtws, nullptr);
    attn_mfma<<<dim3(16, 32), 256, 0, stream>>>(Qws, Kws, Vtws, Ob);
    gemm_mfma<<<dim3(8, 32), 256, 0, stream>>>(Ob, woutT, 1, nullptr, nullptr, nullptr, out);
}

// Round 3
// 202.808 us; speedup vs baseline: 5.9007x; 1.3087x over previous
//
#include <hip/hip_runtime.h>
#include <hip/hip_bf16.h>
#include <stdint.h>

typedef unsigned short u16;
typedef unsigned int u32;
typedef __attribute__((ext_vector_type(8))) short short8;    // 8 bf16 = 4 VGPR (MFMA A/B frag)
typedef __attribute__((ext_vector_type(4))) short short4e;   // 8B packed store
typedef __attribute__((ext_vector_type(4))) float f32x4;     // 16x16 MFMA C/D frag
typedef __attribute__((ext_vector_type(16))) float f32x16;   // 32x32 MFMA C/D frag

constexpr int CB = 2, CS = 2048, CD = 1024, CH = 16, CHD = 64;
constexpr float CSCALE = 0.125f;
constexpr float SC2 = 0.125f * 1.44269504088896f;   // scale * log2(e): exp2 domain
constexpr float DEFER_THR = 11.0f;                   // ~8/ln2: P bounded by 2^11

__device__ __forceinline__ u16 f2bf(float f) {
    unsigned u = __float_as_uint(f);
    u += 0x7fffu + ((u >> 16) & 1u);     // RNE
    return (u16)(u >> 16);
}

#if __has_builtin(__builtin_amdgcn_exp2f)
#define EXP2F(x) __builtin_amdgcn_exp2f(x)
#else
#define EXP2F(x) exp2f(x)
#endif

// pack two f32 -> u32 of 2 bf16 (lo = a, hi = b)
__device__ __forceinline__ u32 pkbf(float a, float b) {
    u32 r;
    asm("v_cvt_pk_bf16_f32 %0, %1, %2" : "=v"(r) : "v"(a), "v"(b));
    return r;
}

// ---------------------------------------------------------------------------
// f32 -> bf16 elementwise (x). 8 elems/thread, exact grid.
// ---------------------------------------------------------------------------
__global__ __launch_bounds__(256) void cvt_x(const float* __restrict__ X, u16* __restrict__ Y) {
    const int i = (blockIdx.x * 256 + threadIdx.x) * 8;
    const float4 v0 = *(const float4*)(X + i);
    const float4 v1 = *(const float4*)(X + i + 4);
    short8 r;
    r[0] = (short)f2bf(v0.x); r[1] = (short)f2bf(v0.y);
    r[2] = (short)f2bf(v0.z); r[3] = (short)f2bf(v0.w);
    r[4] = (short)f2bf(v1.x); r[5] = (short)f2bf(v1.y);
    r[6] = (short)f2bf(v1.z); r[7] = (short)f2bf(v1.w);
    *(short8*)(Y + i) = r;
}

// ---------------------------------------------------------------------------
// Transpose + convert: W [1024][N] f32  ->  Bt [N][1024] bf16.  64x64 tiles.
// ---------------------------------------------------------------------------
__global__ __launch_bounds__(256) void txw(const float* __restrict__ W, u16* __restrict__ Bt,
                                           int ldw) {
    __shared__ u16 T[64][80];
    const int t = threadIdx.x;
    const int n0 = blockIdx.x * 64, k0 = blockIdx.y * 64;
    const int r = t >> 4, c4 = (t & 15) * 4;
#pragma unroll
    for (int p = 0; p < 4; ++p) {
        const int kr = r + p * 16;
        const float4 v = *(const float4*)(W + (size_t)(k0 + kr) * ldw + n0 + c4);
        T[c4 + 0][kr] = f2bf(v.x); T[c4 + 1][kr] = f2bf(v.y);
        T[c4 + 2][kr] = f2bf(v.z); T[c4 + 3][kr] = f2bf(v.w);
    }
    __syncthreads();
    const int rr = t >> 2, cc = (t & 3) * 16;
    const short8 a = *(const short8*)((const char*)&T[0][0] + rr * 160 + cc * 2);
    const short8 b = *(const short8*)((const char*)&T[0][0] + rr * 160 + cc * 2 + 16);
    u16* dst = Bt + (size_t)(n0 + rr) * 1024 + k0 + cc;
    *(short8*)dst = a;
    *(short8*)(dst + 8) = b;
}

// ---------------------------------------------------------------------------
// bf16 MFMA GEMM, 128x128 tile, BK=32, 4 waves (2x2), double-buffered LDS,
// reg-staged global->LDS, 1 barrier per K-step.  K fixed = 1024.
// ---------------------------------------------------------------------------
__global__ __launch_bounds__(256) void gemm_mfma(
    const u16* __restrict__ A, const u16* __restrict__ Bt, int mode,
    u16* __restrict__ Qws, u16* __restrict__ Kws, u16* __restrict__ Vtws,
    float* __restrict__ Cf)
{
    __shared__ u16 SB[2][8192];
    const int tid = threadIdx.x;
    const int w = tid >> 6, lane = tid & 63;
    const int l15 = lane & 15, l4 = lane >> 4;
    const int wr = w >> 1, wc = w & 1;
    const int n0 = blockIdx.x * 128, m0 = blockIdx.y * 128;

    f32x4 acc[4][4];
    const f32x4 zf = {0.f, 0.f, 0.f, 0.f};
#pragma unroll
    for (int i = 0; i < 4; ++i)
#pragma unroll
        for (int j = 0; j < 4; ++j) acc[i][j] = zf;

    short8 stg[4];
#define GEMM_ISSUE(K0)                                                          \
    {                                                                           \
        _Pragma("unroll")                                                       \
        for (int it = 0; it < 4; ++it) {                                        \
            const int c = tid + it * 256;                                       \
            const u16* src;                                                     \
            if (c < 512) { const int row = c >> 2, cs = c & 3;                  \
                src = A + (size_t)(m0 + row) * 1024 + (K0) + cs * 8; }          \
            else { const int c2 = c - 512; const int row = c2 >> 2, cs = c2 & 3;\
                src = Bt + (size_t)(n0 + row) * 1024 + (K0) + cs * 8; }         \
            stg[it] = *(const short8*)src;                                      \
        }                                                                       \
    }
#define GEMM_WRITE(BUF)                                                         \
    {                                                                           \
        _Pragma("unroll")                                                       \
        for (int it = 0; it < 4; ++it) {                                        \
            const int c = tid + it * 256;                                       \
            *(short8*)&SB[BUF][c * 8] = stg[it];                                \
        }                                                                       \
    }

    GEMM_ISSUE(0);
    GEMM_WRITE(0);
    __syncthreads();

    for (int t = 0; t < 32; ++t) {
        const int cur = t & 1;
        if (t < 31) GEMM_ISSUE((t + 1) * 32);

        const u16* Al = &SB[cur][0];
        const u16* Bl = &SB[cur][4096];
        short8 a[4], b[4];
#pragma unroll
        for (int i = 0; i < 4; ++i)
            a[i] = *(const short8*)(Al + (wr * 64 + i * 16 + l15) * 32 + l4 * 8);
#pragma unroll
        for (int j = 0; j < 4; ++j)
            b[j] = *(const short8*)(Bl + (wc * 64 + j * 16 + l15) * 32 + l4 * 8);
#pragma unroll
        for (int i = 0; i < 4; ++i)
#pragma unroll
            for (int j = 0; j < 4; ++j)
                acc[i][j] = __builtin_amdgcn_mfma_f32_16x16x32_bf16(a[i], b[j], acc[i][j], 0, 0, 0);

        if (t < 31) GEMM_WRITE(cur ^ 1);
        __syncthreads();
    }

    // C/D layout (16x16): col = lane&15, row = (lane>>4)*4 + reg.
    if (mode == 1) {
#pragma unroll
        for (int i = 0; i < 4; ++i)
#pragma unroll
            for (int j = 0; j < 4; ++j)
#pragma unroll
                for (int r = 0; r < 4; ++r)
                    Cf[(size_t)(m0 + wr * 64 + i * 16 + l4 * 4 + r) * 1024 +
                       n0 + wc * 64 + j * 16 + l15] = acc[i][j][r];
    } else {
        const int e0 = n0 + wc * 64;
        const int which = e0 >> 10;
        const int h = (e0 >> 6) & 15;
        const int b = m0 >> 11;
        const int sbase = (m0 & 2047) + wr * 64;
        if (which == 2) {
            // V stored TRANSPOSED: Vt[(b*16+h)][hd][s], ld = 2048.
#pragma unroll
            for (int i = 0; i < 4; ++i)
#pragma unroll
                for (int j = 0; j < 4; ++j) {
                    const int hd = j * 16 + l15;
                    const int s4 = sbase + i * 16 + l4 * 4;
                    short4e p;
                    p[0] = (short)f2bf(acc[i][j][0]); p[1] = (short)f2bf(acc[i][j][1]);
                    p[2] = (short)f2bf(acc[i][j][2]); p[3] = (short)f2bf(acc[i][j][3]);
                    *(short4e*)(Vtws + ((size_t)(b * 16 + h) * 64 + hd) * 2048 + s4) = p;
                }
        } else {
            u16* dst = which ? Kws : Qws;
#pragma unroll
            for (int i = 0; i < 4; ++i)
#pragma unroll
                for (int j = 0; j < 4; ++j)
#pragma unroll
                    for (int r = 0; r < 4; ++r) {
                        const int s = sbase + i * 16 + l4 * 4 + r;
                        dst[((size_t)(b * 16 + h) * 2048 + s) * 64 + j * 16 + l15] =
                            f2bf(acc[i][j][r]);
                    }
        }
    }
#undef GEMM_ISSUE
#undef GEMM_WRITE
}

// ---------------------------------------------------------------------------
// MFMA flash attention, swapped-QK^T, in-register softmax (m214-style).
// 4 waves x 32 q-rows (QBLK=128), KVBLK=64, 32x32x16 MFMA.
//   S^T = mfma(K-frag, Q-frag): lane owns ONE q-row (q = q0w + (lane&31)),
//   holding 32 of 64 k-scores (partner lane^32 holds the rest).
//   Row softmax = in-lane reduce + 1 shfl_xor(32).
//   P -> PV A-frags fully in-register: cvt_pk_bf16 + v_permlane32_swap_b32.
//   Defer-max (THR=11 in exp2 domain) makes the O-rescale (cross-lane alpha
//   broadcast via per-warp LDS) rare.
// 1-D grid of 512, complementary (heavy,light) qt pairing for CU balance.
// ---------------------------------------------------------------------------
__global__ __launch_bounds__(256) void attn_mfma32(
    const u16* __restrict__ Qg, const u16* __restrict__ Kg,
    const u16* __restrict__ Vtg, u16* __restrict__ Og)
{
    __shared__ u16 KV[2][8192];    // per buffer: K[64][64] | V^T[64][64], XOR-swizzled
    __shared__ float Aw[4][32];    // per-warp alpha / 1/l broadcast

    const int tid = threadIdx.x;
    const int w = tid >> 6, lane = tid & 63;
    const int l31 = lane & 31, hi = lane >> 5;
    const int bid = blockIdx.x;
    const int kq = bid >> 5, bh = bid & 31;
    const int qt = (kq < 8) ? (15 - kq) : (kq - 8);   // (heavy, light) CU pairs

    const u16* Qp = Qg + (size_t)bh * CS * CHD;
    const u16* Kp = Kg + (size_t)bh * CS * CHD;
    const u16* Vp = Vtg + (size_t)bh * CHD * CS;
    const int q0w = qt * 128 + w * 32;
    const int qrow = q0w + l31;        // this lane's q-row

    // Q B-frags hoisted: Q[q=l31][d = c*16 + hi*8 + j]
    short8 qf[4];
#pragma unroll
    for (int c = 0; c < 4; ++c)
        qf[c] = *(const short8*)(Qp + (size_t)qrow * 64 + c * 16 + hi * 8);

    f32x16 o0, o1;
#pragma unroll
    for (int r = 0; r < 16; ++r) { o0[r] = 0.f; o1[r] = 0.f; }
    float m_run = -1e30f, l_run = 0.f;

    const int nkt = 2 * qt + 2;
    short8 stg[4];

#define ATTN_ISSUE(K0)                                                           \
    {                                                                            \
        _Pragma("unroll")                                                        \
        for (int it = 0; it < 4; ++it) {                                         \
            const int c = tid + it * 256;                                        \
            const int ob = c * 16;                                               \
            const u16* src;                                                      \
            if (ob < 8192) { const int row = ob >> 7, cs = (ob >> 4) & 7;        \
                src = Kp + (size_t)((K0) + row) * 64 + cs * 8; }                 \
            else { const int o2 = ob - 8192; const int row = o2 >> 7,            \
                cs = (o2 >> 4) & 7;                                              \
                src = Vp + (size_t)row * CS + (K0) + cs * 8; }                   \
            stg[it] = *(const short8*)src;                                       \
        }                                                                        \
    }
#define ATTN_WRITE(BUF)                                                          \
    {                                                                            \
        _Pragma("unroll")                                                        \
        for (int it = 0; it < 4; ++it) {                                         \
            const int c = tid + it * 256;                                        \
            const int ob = c * 16;                                               \
            int db;                                                              \
            if (ob < 8192) { const int row = ob >> 7; db = ob ^ ((row & 7) << 4); } \
            else { const int o2 = ob - 8192; const int row = o2 >> 7;            \
                db = 8192 + (o2 ^ ((row & 7) << 4)); }                           \
            *(short8*)((char*)&KV[BUF][0] + db) = stg[it];                       \
        }                                                                        \
    }

    ATTN_ISSUE(0);
    ATTN_WRITE(0);
    __syncthreads();

    for (int kt = 0; kt < nkt; ++kt) {
        const int k0 = kt * 64;
        const int cur = kt & 1;
        if (kt + 1 < nkt) ATTN_ISSUE((kt + 1) * 64);

        if (k0 <= q0w + 31) {
            const char* Kl = (const char*)&KV[cur][0];
            const char* Vl = (const char*)&KV[cur][4096];

            // ---- S^T = K * Q^T : D[k][q], acc col = q = l31 (verified 32x32 C layout)
            f32x16 s0, s1;
#pragma unroll
            for (int r = 0; r < 16; ++r) { s0[r] = 0.f; s1[r] = 0.f; }
#pragma unroll
            for (int c = 0; c < 4; ++c) {
                const int row = l31;   // kh=0
                const short8 kf = *(const short8*)(Kl + row * 128 +
                                    ((c * 32 + hi * 16) ^ ((row & 7) << 4)));
                s0 = __builtin_amdgcn_mfma_f32_32x32x16_bf16(kf, qf[c], s0, 0, 0, 0);
            }
#pragma unroll
            for (int c = 0; c < 4; ++c) {
                const int row = 32 + l31;  // kh=1
                const short8 kf = *(const short8*)(Kl + row * 128 +
                                    ((c * 32 + hi * 16) ^ ((row & 7) << 4)));
                s1 = __builtin_amdgcn_mfma_f32_32x32x16_bf16(kf, qf[c], s1, 0, 0, 0);
            }

            // ---- scale (exp2 domain) + causal mask + row max
            const bool edge = (k0 + 63 > q0w);
            float pmax = -1e30f;
#pragma unroll
            for (int r = 0; r < 16; ++r) {
                float a0 = s0[r] * SC2, a1 = s1[r] * SC2;
                if (edge) {
                    const int koff = (r & 3) + 8 * (r >> 2) + 4 * hi;  // crow(r,hi)
                    if (k0 + koff > qrow) a0 = -1e30f;
                    if (k0 + 32 + koff > qrow) a1 = -1e30f;
                }
                s0[r] = a0; s1[r] = a1;
                pmax = fmaxf(pmax, fmaxf(a0, a1));
            }
            pmax = fmaxf(pmax, __shfl_xor(pmax, 32));

            // ---- defer-max: rescale only when the running max grew too much
            if (!__all(pmax - m_run <= DEFER_THR)) {
                const float mn = fmaxf(m_run, pmax);
                const float al = EXP2F(m_run - mn);
                l_run *= al;
                m_run = mn;
                if (lane < 32) Aw[w][l31] = al;      // alpha per q-row
                asm volatile("" ::: "memory");
#pragma unroll
                for (int g = 0; g < 4; ++g) {
                    const f32x4 av = *(const f32x4*)&Aw[w][g * 8 + hi * 4];
#pragma unroll
                    for (int c = 0; c < 4; ++c) {
                        o0[g * 4 + c] *= av[c];
                        o1[g * 4 + c] *= av[c];
                    }
                }
            }

            // ---- P = exp2(s - m_run), row-sum
            float lsum = 0.f;
#pragma unroll
            for (int r = 0; r < 16; ++r) {
                const float p0 = EXP2F(s0[r] - m_run);
                const float p1 = EXP2F(s1[r] - m_run);
                s0[r] = p0; s1[r] = p1;
                lsum += p0 + p1;
            }
            lsum += __shfl_xor(lsum, 32);
            l_run += lsum;

            // ---- P -> A-frags (in-register, T12) + PV
#pragma unroll
            for (int ks = 0; ks < 4; ++ks) {
                const int rb = (ks & 1) * 8;
                const f32x16& sv = (ks < 2) ? s0 : s1;
                u32 w0 = pkbf(sv[rb + 0], sv[rb + 1]);
                u32 w1 = pkbf(sv[rb + 2], sv[rb + 3]);
                u32 w2 = pkbf(sv[rb + 4], sv[rb + 5]);
                u32 w3 = pkbf(sv[rb + 6], sv[rb + 7]);
                // swap: upper half of dst <-> lower half of src =>
                // {w0,w2} -> pa words 0,2 ; {w1,w3} -> pa words 1,3
                asm("v_permlane32_swap_b32 %0, %1" : "+v"(w0), "+v"(w2));
                asm("v_permlane32_swap_b32 %0, %1" : "+v"(w1), "+v"(w3));
                union { u32 uw[4]; short8 v; } pu;
                pu.uw[0] = w0; pu.uw[1] = w1; pu.uw[2] = w2; pu.uw[3] = w3;
                const short8 pa = pu.v;

                const int vr0 = l31, vr1 = 32 + l31;
                const short8 v0 = *(const short8*)(Vl + vr0 * 128 +
                                    ((ks * 32 + hi * 16) ^ ((vr0 & 7) << 4)));
                const short8 v1 = *(const short8*)(Vl + vr1 * 128 +
                                    ((ks * 32 + hi * 16) ^ ((vr1 & 7) << 4)));
                o0 = __builtin_amdgcn_mfma_f32_32x32x16_bf16(pa, v0, o0, 0, 0, 0);
                o1 = __builtin_amdgcn_mfma_f32_32x32x16_bf16(pa, v1, o1, 0, 0, 0);
            }
        }

        if (kt + 1 < nkt) ATTN_WRITE(cur ^ 1);
        __syncthreads();
    }

    // ---- normalize (1/l broadcast) + store O bf16 in [B][S][D]
    if (lane < 32) Aw[w][l31] = 1.f / l_run;
    asm volatile("" ::: "memory");
    const int b = bh >> 4, h = bh & 15;
#pragma unroll
    for (int g = 0; g < 4; ++g) {
        const f32x4 iv = *(const f32x4*)&Aw[w][g * 8 + hi * 4];
#pragma unroll
        for (int c = 0; c < 4; ++c) {
            const int q = q0w + 8 * g + 4 * hi + c;    // crow(4g+c, hi)
            u16* dst = Og + ((size_t)(b * CS + q)) * CD + h * 64 + l31;
            dst[0]  = f2bf(o0[g * 4 + c] * iv[c]);
            dst[32] = f2bf(o1[g * 4 + c] * iv[c]);
        }
    }
#undef ATTN_ISSUE
#undef ATTN_WRITE
}

// ---------------------------------------------------------------------------
extern "C" void kernel_launch(void* const* d_in, const int* in_sizes, int n_in,
                              void* d_out, int out_size, void* d_ws, size_t ws_size,
                              hipStream_t stream)
{
    const float* x     = (const float*)d_in[0];   // (B,S,D)
    const float* w_qkv = (const float*)d_in[1];   // (D,3D)
    const float* w_out = (const float*)d_in[2];   // (D,D)
    float* out = (float*)d_out;                   // (B,S,D) f32

    u16* xb    = (u16*)d_ws;                      // [4096][1024]
    u16* wqkvT = xb    + (size_t)4096 * 1024;     // [3072][1024]
    u16* woutT = wqkvT + (size_t)3072 * 1024;     // [1024][1024]
    u16* Qws   = woutT + (size_t)1024 * 1024;     // [32][2048][64]
    u16* Kws   = Qws   + (size_t)32 * 2048 * 64;
    u16* Vtws  = Kws   + (size_t)32 * 2048 * 64;  // [32][64][2048]
    u16* Ob    = Vtws  + (size_t)32 * 2048 * 64;  // [4096][1024]

    cvt_x<<<2048, 256, 0, stream>>>(x, xb);
    txw<<<dim3(48, 16), 256, 0, stream>>>(w_qkv, wqkvT, 3072);
    txw<<<dim3(16, 16), 256, 0, stream>>>(w_out, woutT, 1024);

    gemm_mfma<<<dim3(24, 32), 256, 0, stream>>>(xb, wqkvT, 0, Qws, Kws, Vtws, nullptr);
    attn_mfma32<<<512, 256, 0, stream>>>(Qws, Kws, Vtws, Ob);
    gemm_mfma<<<dim3(8, 32), 256, 0, stream>>>(Ob, woutT, 1, nullptr, nullptr, nullptr, out);
}